// Round 6
// baseline (4698.822 us; speedup 1.0000x reference)
//
#include <hip/hip_runtime.h>

// Problem: new_LSTM_30365418783418  (B=128, T=256, I=512, H=1024)
// R10 = R9 resubmit (container-level infra failure last round; kernel audit
// found no hang/OOB). Fuse the input GEMM into the persistent recurrence.
//  - Block nb consumes exactly the P-slice it can produce (x_t @ Wi_slice),
//    so each block computes its own x-preacts for step t+1 in the barrier
//    slack (Wi fragments in LDS, Pbuf bf16 double-buffer in LDS). gemm_pre
//    and the global P buffer are gone from the fast path; x/x_d L3-resident.
//  - Barrier: 1 atomicAdd arrival per block; LAST arriver posts 'release';
//    all waves poll the single release word (coalesced). No gather wave.
//  - LDS: Wh frags 64KB + Wi frags 32KB + Pls 10.5KB + Pbuf 10.5KB + cs 2.5KB
//    = ~120KB static (<160KB/WG; 77KB already proven in R6-R8).
//
// d_in: 0:x 1:x_d 2:hidden 3:cell | 4..9: Wii,Wif,Wig,Wio,Wid,Wro (H,I)
//       10..14: Whi,Whf,Whg,Who,Whd (H,H) | 15..20: bi,bf,bg,bo,bd,Wrb (H,)
// d_out: y(128,256,1024) ++ h_last(128,1024) ++ c_last(128,1024), float32.

using bf16x8 = __attribute__((ext_vector_type(8))) __bf16;
using f32x4  = __attribute__((ext_vector_type(4))) float;

#define MFMA16(a, b, c) __builtin_amdgcn_mfma_f32_16x16x32_bf16(a, b, c, 0, 0, 0)

static __device__ __forceinline__ float b2f(ushort u) {
  union { unsigned int i; float f; } v; v.i = ((unsigned int)u) << 16; return v.f;
}
static __device__ __forceinline__ ushort f2b(float f) {
  union { float f; unsigned int i; } v; v.f = f;
  unsigned int x = v.i;
  return (ushort)((x + 0x7fffu + ((x >> 16) & 1u)) >> 16);  // RNE
}
static __device__ __forceinline__ float sigm(float x) {
  return 1.0f / (1.0f + __expf(-x));
}
static __device__ __forceinline__ float tanhfast(float x) {
  float e = __expf(2.0f * x);          // tanh = 1 - 2/(e^{2x}+1); saturates
  return 1.0f - 2.0f / (e + 1.0f);
}

// ---------------------------------------------------------------------------
// f32 -> bf16 conversion, 4 elems/thread. n % 4 == 0.
// ---------------------------------------------------------------------------
__global__ __launch_bounds__(256) void cvt_kernel(const float* __restrict__ src,
                                                  ushort* __restrict__ dst, int n)
{
  int i = (blockIdx.x * 256 + threadIdx.x) * 4;
  if (i < n) {
    float4 v = *(const float4*)(src + i);
    ushort4 o;
    o.x = f2b(v.x); o.y = f2b(v.y); o.z = f2b(v.z); o.w = f2b(v.w);
    *(ushort4*)(dst + i) = o;
  }
}

// ---------------------------------------------------------------------------
// Generic 128x128 NT bf16 GEMM K-loop, plain-load LDS staging.
// ---------------------------------------------------------------------------
static __device__ __forceinline__ void gemm_kloop(
    const ushort* __restrict__ A, int lda,
    const ushort* __restrict__ Bw, int ldb, int K,
    ushort* As, ushort* Bs, f32x4 (&acc)[4][4])
{
  const int tid = threadIdx.x;
  const int l = tid & 63, w = tid >> 6;
  const int wm = (w >> 1) * 64, wn = (w & 1) * 64;
  const int lr = l & 15, quad = l >> 4;
  bf16x8* Asv = (bf16x8*)As;
  bf16x8* Bsv = (bf16x8*)Bs;
  for (int k0 = 0; k0 < K; k0 += 32) {
    __syncthreads();
#pragma unroll
    for (int it = 0; it < 2; ++it) {
      int c = it * 256 + tid;
      int row = c >> 2, seg = c & 3;
      Asv[c] = *(const bf16x8*)(A  + row * lda + k0 + seg * 8);
      Bsv[c] = *(const bf16x8*)(Bw + row * ldb + k0 + seg * 8);
    }
    __syncthreads();
    bf16x8 af[4], bfr[4];
#pragma unroll
    for (int i = 0; i < 4; ++i) af[i]  = Asv[(wm + i * 16 + lr) * 4 + quad];
#pragma unroll
    for (int j = 0; j < 4; ++j) bfr[j] = Bsv[(wn + j * 16 + lr) * 4 + quad];
#pragma unroll
    for (int i = 0; i < 4; ++i)
#pragma unroll
      for (int j = 0; j < 4; ++j)
        acc[i][j] = MFMA16(af[i], bfr[j], acc[i][j]);
  }
}

// ---------------------------------------------------------------------------
// Fallback kernel 1 (per step): P[b][g*1024+h] = bf16(x_t . Wg + bias).
// Grid (1, 40), 256 threads. Only used if cooperative launch fails.
// ---------------------------------------------------------------------------
__global__ __launch_bounds__(256) void gemm_pre(
    const ushort* __restrict__ xb, const ushort* __restrict__ xdb,
    const ushort* __restrict__ Wb,      // 6x(1024x512) contiguous (Wii..Wid,Wro)
    const float* __restrict__ bias5, ushort* __restrict__ P, int t0)
{
  __shared__ __align__(16) ushort As[4096], Bs[4096];
  const int m0 = blockIdx.x * 128;
  const int n0 = blockIdx.y * 128;
  const int g = n0 >> 10;
  const ushort* A = (g == 4) ? xdb : xb;
  const ushort* Bw = Wb + g * 524288 + (n0 & 1023) * 512;

  const int tid = threadIdx.x;
  const int l = tid & 63, w = tid >> 6;
  const int wm = (w >> 1) * 64, wn = (w & 1) * 64;
  const int lr = l & 15, quad = l >> 4;
  f32x4 acc[4][4] = {};
  bf16x8* Asv = (bf16x8*)As;
  bf16x8* Bsv = (bf16x8*)Bs;

  for (int k0 = 0; k0 < 512; k0 += 32) {
    __syncthreads();
#pragma unroll
    for (int it = 0; it < 2; ++it) {
      int c = it * 256 + tid;
      int row = c >> 2, seg = c & 3;
      int gr = m0 + row;                          // m' = b  (chunk=1)
      int arow = gr * 256 + t0;                   // b*T + t
      Asv[c] = *(const bf16x8*)(A  + arow * 512 + k0 + seg * 8);
      Bsv[c] = *(const bf16x8*)(Bw + row  * 512 + k0 + seg * 8);
    }
    __syncthreads();
    bf16x8 af[4], bfr[4];
#pragma unroll
    for (int i = 0; i < 4; ++i) af[i]  = Asv[(wm + i * 16 + lr) * 4 + quad];
#pragma unroll
    for (int j = 0; j < 4; ++j) bfr[j] = Bsv[(wn + j * 16 + lr) * 4 + quad];
#pragma unroll
    for (int i = 0; i < 4; ++i)
#pragma unroll
      for (int j = 0; j < 4; ++j)
        acc[i][j] = MFMA16(af[i], bfr[j], acc[i][j]);
  }

#pragma unroll
  for (int i = 0; i < 4; ++i)
#pragma unroll
    for (int j = 0; j < 4; ++j) {
      int row = m0 + wm + i * 16 + quad * 4;   // C/D: row = quad*4+reg (m89)
      int col = n0 + wn + j * 16 + lr;         //      col = lane&15
      float bias = bias5[col];
#pragma unroll
      for (int r = 0; r < 4; ++r)
        P[(row + r) * 5120 + col] = f2b(acc[i][j][r] + bias);
    }
}

// ---------------------------------------------------------------------------
// R10 persistent fused kernel (cooperative). Grid 256 x 256 threads.
// Block nb owns h-cols nb*4..+3, all 5 gates.
//   Wh fragments (20 rows, K=1024) -> Bs0/Bs1 LDS (loaded once).
//   Wi fragments (20 rows, K=512)  -> Wi0/Wi1 LDS (loaded once).
// Per step t: Pls = h_{t-1} @ Wh^T (MFMA); elementwise uses Pls + Pbuf[t&1]
// (x-preacts computed one step ahead in barrier slack); h_t -> hs via
// agent-scope relaxed write-through stores.
// Barrier: atomicAdd arrival; last arriver posts release; everyone polls it.
// ---------------------------------------------------------------------------
__global__ __launch_bounds__(256, 1) void lstm_fused(
    const ushort* __restrict__ h0, float* __restrict__ cbuf,
    const ushort* __restrict__ Whb, const ushort* __restrict__ Wib,
    const ushort* __restrict__ xb, const ushort* __restrict__ xdb,
    const float* __restrict__ bias5, ushort* __restrict__ hs,
    unsigned int* __restrict__ ctr, unsigned int* __restrict__ release,
    int nt)
{
  __shared__ __align__(16) ushort Bs0[32 * 64 * 8];   // 32KB Wh gates i,f,g,o
  __shared__ __align__(16) ushort Bs1[32 * 64 * 8];   // 32KB Wh gate d (+0s)
  __shared__ __align__(16) ushort Wi0[16 * 64 * 8];   // 16KB Wi gates i,f,g,o
  __shared__ __align__(16) ushort Wi1[16 * 64 * 8];   // 16KB Wi gate d (+0s)
  __shared__ float  Pls[128 * 21];                    // h@Wh preacts, pad 21
  __shared__ ushort Pbuf[2][128 * 21];                // x@Wi+bias, bf16, dbuf
  __shared__ float  cs[128 * 5];                      // cell slice, pad 5

  const int tid = threadIdx.x;
  const int l = tid & 63, w = tid >> 6;
  const int lr = l & 15, quad = l >> 4;
  const int nb = blockIdx.x;                          // 0..255
  const unsigned int nblk = gridDim.x;                // 256

  // ---- Wh fragments -> Bs0/Bs1 (once) ----
  {
    const ushort* wp = Whb + (((lr >> 2) << 10) + nb * 4 + (lr & 3)) * 1024 + quad * 8;
#pragma unroll
    for (int kk = 0; kk < 8; ++kk) {
      int k = w * 8 + kk;
      *(bf16x8*)(Bs0 + (k * 64 + l) * 8) = *(const bf16x8*)(wp + k * 32);
    }
  }
  {
    const ushort* wp = Whb + (4096 + nb * 4 + (lr & 3)) * 1024 + quad * 8;
#pragma unroll
    for (int kk = 0; kk < 8; ++kk) {
      int k = w * 8 + kk;
      bf16x8 v = {};
      if (lr < 4) v = *(const bf16x8*)(wp + k * 32);
      *(bf16x8*)(Bs1 + (k * 64 + l) * 8) = v;
    }
  }
  // ---- Wi fragments -> Wi0/Wi1 (once); Wib = 6x(1024x512), gate g at
  //      g*524288, row h stride 512 ----
  {
    const ushort* wp = Wib + (lr >> 2) * 524288 + (nb * 4 + (lr & 3)) * 512 + quad * 8;
#pragma unroll
    for (int kk = 0; kk < 4; ++kk) {
      int k = w * 4 + kk;
      *(bf16x8*)(Wi0 + (k * 64 + l) * 8) = *(const bf16x8*)(wp + k * 32);
    }
  }
  {
    const ushort* wp = Wib + 4 * 524288 + (nb * 4 + (lr & 3)) * 512 + quad * 8;
#pragma unroll
    for (int kk = 0; kk < 4; ++kk) {
      int k = w * 4 + kk;
      bf16x8 v = {};
      if (lr < 4) v = *(const bf16x8*)(wp + k * 32);
      *(bf16x8*)(Wi1 + (k * 64 + l) * 8) = v;
    }
  }
  // ---- biases per lane (col = gate(lr>>2), hc(lr&3)) ----
  const float b0l = bias5[((lr >> 2) << 10) + nb * 4 + (lr & 3)];
  const float b1l = (lr < 4) ? bias5[4096 + nb * 4 + lr] : 0.0f;
  // ---- cell slice -> LDS ----
  if (tid < 128) {
    float4 cv = *(const float4*)(cbuf + tid * 1024 + nb * 4);
    cs[tid * 5 + 0] = cv.x; cs[tid * 5 + 1] = cv.y;
    cs[tid * 5 + 2] = cv.z; cs[tid * 5 + 3] = cv.w;
  }
  __syncthreads();

  const bf16x8* B0v = (const bf16x8*)Bs0;
  const bf16x8* B1v = (const bf16x8*)Bs1;
  const bf16x8* W0v = (const bf16x8*)Wi0;
  const bf16x8* W1v = (const bf16x8*)Wi1;

  // elementwise mapping: thread -> (batch row eb, col pair hp)
  const int eb = tid >> 1;
  const int hp = (tid & 1) * 2;

  // pre-GEMM: Pbuf[pb][b][0..19] = x_t @ Wi^T + bias (d-gate uses x_d)
  auto pregemm = [&](int t, int pb) {
    const ushort* ax = xb  + (w * 32 + lr) * 131072 + t * 512 + quad * 8;
    const ushort* ad = xdb + (w * 32 + lr) * 131072 + t * 512 + quad * 8;
    f32x4 ap[2][2] = {};
#pragma unroll
    for (int k = 0; k < 16; ++k) {
      bf16x8 x0 = *(const bf16x8*)(ax + k * 32);
      bf16x8 x1 = *(const bf16x8*)(ax + 16 * 131072 + k * 32);
      bf16x8 d0 = *(const bf16x8*)(ad + k * 32);
      bf16x8 d1 = *(const bf16x8*)(ad + 16 * 131072 + k * 32);
      bf16x8 w0 = W0v[k * 64 + l];
      bf16x8 w1 = W1v[k * 64 + l];
      ap[0][0] = MFMA16(x0, w0, ap[0][0]);
      ap[1][0] = MFMA16(x1, w0, ap[1][0]);
      ap[0][1] = MFMA16(d0, w1, ap[0][1]);
      ap[1][1] = MFMA16(d1, w1, ap[1][1]);
    }
    ushort* dst = Pbuf[pb];
#pragma unroll
    for (int i = 0; i < 2; ++i) {
      int b = w * 32 + i * 16 + quad * 4;
#pragma unroll
      for (int r = 0; r < 4; ++r)
        dst[(b + r) * 21 + lr] = f2b(ap[i][0][r] + b0l);
      if (lr < 4) {
#pragma unroll
        for (int r = 0; r < 4; ++r)
          dst[(b + r) * 21 + 16 + lr] = f2b(ap[i][1][r] + b1l);
      }
    }
  };

  // prologue: x-preacts for step 0
  pregemm(0, 0);

  for (int tt = 0; tt < nt; ++tt) {
    const int t = tt;
    // ---- phase 1: recurrence k-loop (h_{t-1} @ Wh^T) ----
    const ushort* base;
    int rs;
    if (t == 0) { base = h0;                  rs = 1024;   }
    else        { base = hs + (t - 1) * 1024; rs = 262144; }
    const ushort* a0p = base + (w * 32 + lr) * rs + quad * 8;
    const ushort* a1p = a0p + 16 * rs;

    f32x4 acc[2][2] = {};
#pragma unroll
    for (int k = 0; k < 32; ++k) {
      bf16x8 a0 = *(const bf16x8*)(a0p + k * 32);
      bf16x8 a1 = *(const bf16x8*)(a1p + k * 32);
      bf16x8 b0 = B0v[k * 64 + l];
      bf16x8 b1 = B1v[k * 64 + l];
      acc[0][0] = MFMA16(a0, b0, acc[0][0]);
      acc[1][0] = MFMA16(a1, b0, acc[1][0]);
      acc[0][1] = MFMA16(a0, b1, acc[0][1]);
      acc[1][1] = MFMA16(a1, b1, acc[1][1]);
    }

    // ---- phase 2: Pls exchange (C/D m89: row = quad*4+reg, col = lane&15)
#pragma unroll
    for (int i = 0; i < 2; ++i) {
      int b = w * 32 + i * 16 + quad * 4;
#pragma unroll
      for (int r = 0; r < 4; ++r)
        Pls[(b + r) * 21 + lr] = acc[i][0][r];
      if (lr < 4) {
#pragma unroll
        for (int r = 0; r < 4; ++r)
          Pls[(b + r) * 21 + 16 + lr] = acc[i][1][r];
      }
    }
    __syncthreads();

    // ---- phase 3: elementwise, h-store (agent-scope write-through) ----
    {
      const float*  pr = Pls + eb * 21;
      const ushort* pp = Pbuf[tt & 1] + eb * 21;
      float pi0 = b2f(pp[0 + hp])  + pr[0 + hp];
      float pi1 = b2f(pp[1 + hp])  + pr[1 + hp];
      float pf0 = b2f(pp[4 + hp])  + pr[4 + hp];
      float pf1 = b2f(pp[5 + hp])  + pr[5 + hp];
      float pg0 = b2f(pp[8 + hp])  + pr[8 + hp];
      float pg1 = b2f(pp[9 + hp])  + pr[9 + hp];
      float po0 = b2f(pp[12 + hp]) + pr[12 + hp];
      float po1 = b2f(pp[13 + hp]) + pr[13 + hp];
      float pd0 = b2f(pp[16 + hp]) + pr[16 + hp];
      float pd1 = b2f(pp[17 + hp]) + pr[17 + hp];
      float c0 = cs[eb * 5 + hp], c1 = cs[eb * 5 + hp + 1];
      float cn0 = sigm(pf0) * c0 + sigm(pi0) * tanhfast(pg0) + sigm(pd0);
      float cn1 = sigm(pf1) * c1 + sigm(pi1) * tanhfast(pg1) + sigm(pd1);
      cs[eb * 5 + hp] = cn0;
      cs[eb * 5 + hp + 1] = cn1;
      union { ushort2 s; unsigned int u; } hu;
      hu.s.x = f2b(sigm(po0) * tanhfast(cn0));
      hu.s.y = f2b(sigm(po1) * tanhfast(cn1));
      __hip_atomic_store(
          (unsigned int*)(hs + (eb * 256 + t) * 1024 + nb * 4 + hp),
          hu.u, __ATOMIC_RELAXED, __HIP_MEMORY_SCOPE_AGENT);
    }

    if (tt + 1 < nt) {
      const unsigned int g = (unsigned int)(t + 1);
      // ---- phase 4: arrival (syncthreads drains every wave's vmcnt) ----
      __syncthreads();
      if (tid == 0) {
        asm volatile("s_waitcnt vmcnt(0)" ::: "memory");
        unsigned int old = __hip_atomic_fetch_add(ctr, 1u, __ATOMIC_RELAXED,
                                                  __HIP_MEMORY_SCOPE_AGENT);
        if (old == g * nblk - 1u)   // last arriver posts release
          __hip_atomic_store(release, g, __ATOMIC_RELAXED,
                             __HIP_MEMORY_SCOPE_AGENT);
      }
      // ---- phase 5: pre-GEMM for step t+1 (fills barrier slack) ----
      pregemm(tt + 1, (tt + 1) & 1);
      // ---- phase 6: poll release (wave-coalesced single word) ----
      while (__hip_atomic_load(release, __ATOMIC_RELAXED,
                               __HIP_MEMORY_SCOPE_AGENT) < g) {
        __builtin_amdgcn_s_sleep(1);
      }
      asm volatile("" ::: "memory");   // no load hoisting above the poll
    }
  }

  // ---- cell slice back to global (each thread wrote its own cs entries) ----
  *(float2*)(cbuf + eb * 1024 + nb * 4 + hp) = *(float2*)(cs + eb * 5 + hp);
}

// ---------------------------------------------------------------------------
// Fallback kernel 2 (x256): one LSTM step from global P. Grid (4,64) x 64.
// ---------------------------------------------------------------------------
__global__ __launch_bounds__(64) void lstm_step(
    const ushort* __restrict__ h0, float* __restrict__ cbuf,
    const ushort* __restrict__ Whb, const ushort* __restrict__ P,
    ushort* __restrict__ hs, int t)
{
  const int l = threadIdx.x;
  const int m0 = blockIdx.x * 32;
  const int hc = blockIdx.y * 16;
  const int lr = l & 15, quad = l >> 4;

  const ushort* base;
  int rs;
  if (t == 0) { base = h0;                  rs = 1024;   }
  else        { base = hs + (t - 1) * 1024; rs = 262144; }

  f32x4 acc[2][5] = {};
  const ushort* a0p = base + (m0 + lr) * rs + quad * 8;
  const ushort* a1p = a0p + 16 * rs;
  const ushort* wp = Whb + (hc + lr) * 1024 + quad * 8;

#pragma unroll 2
  for (int k0 = 0; k0 < 1024; k0 += 32) {
    bf16x8 a0 = *(const bf16x8*)(a0p + k0);
    bf16x8 a1 = *(const bf16x8*)(a1p + k0);
    bf16x8 b0 = *(const bf16x8*)(wp + k0);
    bf16x8 b1 = *(const bf16x8*)(wp + 1048576 + k0);
    bf16x8 b2 = *(const bf16x8*)(wp + 2097152 + k0);
    bf16x8 b3 = *(const bf16x8*)(wp + 3145728 + k0);
    bf16x8 b4 = *(const bf16x8*)(wp + 4194304 + k0);
    acc[0][0] = MFMA16(a0, b0, acc[0][0]);
    acc[1][0] = MFMA16(a1, b0, acc[1][0]);
    acc[0][1] = MFMA16(a0, b1, acc[0][1]);
    acc[1][1] = MFMA16(a1, b1, acc[1][1]);
    acc[0][2] = MFMA16(a0, b2, acc[0][2]);
    acc[1][2] = MFMA16(a1, b2, acc[1][2]);
    acc[0][3] = MFMA16(a0, b3, acc[0][3]);
    acc[1][3] = MFMA16(a1, b3, acc[1][3]);
    acc[0][4] = MFMA16(a0, b4, acc[0][4]);
    acc[1][4] = MFMA16(a1, b4, acc[1][4]);
  }

  const int h = hc + lr;
#pragma unroll
  for (int i = 0; i < 2; ++i) {
#pragma unroll
    for (int r = 0; r < 4; ++r) {
      int b = m0 + i * 16 + quad * 4 + r;
      int prow = b * 5120;
      float pi = b2f(P[prow + h])          + acc[i][0][r];
      float pf = b2f(P[prow + 1024 + h])   + acc[i][1][r];
      float pg = b2f(P[prow + 2048 + h])   + acc[i][2][r];
      float po = b2f(P[prow + 3072 + h])   + acc[i][3][r];
      float pd = b2f(P[prow + 4096 + h])   + acc[i][4][r];
      float ig = sigm(pi), fg = sigm(pf), gg = tanhfast(pg);
      float og = sigm(po), dg = sigm(pd);
      float cold = cbuf[b * 1024 + h];
      float cnew = fg * cold + ig * gg + dg;
      cbuf[b * 1024 + h] = cnew;
      hs[(b * 256 + t) * 1024 + h] = f2b(og * tanhfast(cnew));
    }
  }
}

// ---------------------------------------------------------------------------
// Kernel 3: y = tanh(x@Wro^T + hs@Who^T + Wrb), f32 out. Grid (256, 8).
// ---------------------------------------------------------------------------
__global__ __launch_bounds__(256) void gemm_post(
    const ushort* __restrict__ xb, const ushort* __restrict__ hs,
    const ushort* __restrict__ Wrob, const ushort* __restrict__ Whob,
    const float* __restrict__ Wrb, float* __restrict__ y)
{
  __shared__ __align__(16) ushort As[4096], Bs[4096];
  const int m0 = blockIdx.x * 128;
  const int n0 = blockIdx.y * 128;
  f32x4 acc[4][4] = {};
  gemm_kloop(xb + m0 * 512,  512,  Wrob + n0 * 512,  512,  512,  As, Bs, acc);
  gemm_kloop(hs + m0 * 1024, 1024, Whob + n0 * 1024, 1024, 1024, As, Bs, acc);

  const int tid = threadIdx.x;
  const int l = tid & 63, w = tid >> 6;
  const int wm = (w >> 1) * 64, wn = (w & 1) * 64;
  const int lr = l & 15, quad = l >> 4;
#pragma unroll
  for (int i = 0; i < 4; ++i)
#pragma unroll
    for (int j = 0; j < 4; ++j) {
      int row = m0 + wm + i * 16 + quad * 4;
      int col = n0 + wn + j * 16 + lr;
      float bias = Wrb[col];
#pragma unroll
      for (int r = 0; r < 4; ++r)
        y[(row + r) * 1024 + col] = tanhfast(acc[i][j][r] + bias);
    }
}

// ---------------------------------------------------------------------------
// finish: h_last (= hs[:,255,:], bf16->f32) and c_last (f32) into d_out tail.
// ---------------------------------------------------------------------------
__global__ __launch_bounds__(256) void finish_kernel(
    const ushort* __restrict__ hs, const float* __restrict__ cbuf,
    float* __restrict__ out_tail)
{
  int i = blockIdx.x * 256 + threadIdx.x;
  if (i < 131072) {
    int b = i >> 10, h = i & 1023;
    out_tail[i] = b2f(hs[(b * 256 + 255) * 1024 + h]);
    out_tail[131072 + i] = cbuf[i];
  }
}

// ---------------------------------------------------------------------------
extern "C" void kernel_launch(void* const* d_in, const int* in_sizes, int n_in,
                              void* d_out, int out_size, void* d_ws, size_t ws_size,
                              hipStream_t stream)
{
  const float* x   = (const float*)d_in[0];
  const float* xd  = (const float*)d_in[1];
  const float* hid = (const float*)d_in[2];
  const float* cel = (const float*)d_in[3];
  const float* Win[6] = {(const float*)d_in[4], (const float*)d_in[5],
                         (const float*)d_in[6], (const float*)d_in[7],
                         (const float*)d_in[8], (const float*)d_in[9]};
  const float* Whn[5] = {(const float*)d_in[10], (const float*)d_in[11],
                         (const float*)d_in[12], (const float*)d_in[13],
                         (const float*)d_in[14]};
  const float* bia[5] = {(const float*)d_in[15], (const float*)d_in[16],
                         (const float*)d_in[17], (const float*)d_in[18],
                         (const float*)d_in[19]};
  const float* Wrb = (const float*)d_in[20];
  float* y = (float*)d_out;

  // ws carve (bytes):
  char* ws = (char*)d_ws;
  ushort* xb    = (ushort*)(ws);                  //  33,554,432
  ushort* xdb   = (ushort*)(ws + 33554432);       //  33,554,432
  ushort* Wb    = (ushort*)(ws + 67108864);       //   6,291,456 (6x 1024x512)
  ushort* Whb   = (ushort*)(ws + 73400320);       //  10,485,760 (5x 1024x1024)
  ushort* hs    = (ushort*)(ws + 83886080);       //  67,108,864
  ushort* h0    = (ushort*)(ws + 150994944);      //     262,144
  float*  cbuf  = (float*) (ws + 151519232);      //     524,288
  float*  bias5 = (float*) (ws + 152043520);      //      20,480
  unsigned int* flags = (unsigned int*)(ws + 152064000);  // 4,096 (barrier)
  unsigned int* ctr     = flags;
  unsigned int* release = flags + 128;            // separate cache line
  ushort* P     = (ushort*)(ws + 152068096);      //   1,310,720 (fallback only)

  // --- conversions f32 -> bf16 ---
  cvt_kernel<<<16384, 256, 0, stream>>>(x,  xb,  16777216);
  cvt_kernel<<<16384, 256, 0, stream>>>(xd, xdb, 16777216);
  for (int i = 0; i < 6; ++i)
    cvt_kernel<<<512, 256, 0, stream>>>(Win[i], Wb + i * 524288, 524288);
  for (int i = 0; i < 5; ++i)
    cvt_kernel<<<1024, 256, 0, stream>>>(Whn[i], Whb + i * 1048576, 1048576);
  cvt_kernel<<<128, 256, 0, stream>>>(hid, h0, 131072);
  hipMemcpyAsync(cbuf, cel, 131072 * 4, hipMemcpyDeviceToDevice, stream);
  for (int i = 0; i < 5; ++i)
    hipMemcpyAsync(bias5 + i * 1024, bia[i], 4096, hipMemcpyDeviceToDevice, stream);
  hipMemsetAsync(flags, 0, 4096, stream);   // reset ctr/release per run

  // --- recurrence: single fused cooperative launch ---
  int nt = 256;
  void* args[] = {&h0, &cbuf, &Whb, &Wb, &xb, &xdb, &bias5, &hs,
                  &ctr, &release, &nt};
  hipError_t e = hipLaunchCooperativeKernel((const void*)lstm_fused,
                                            dim3(256), dim3(256),
                                            args, 0, stream);
  if (e != hipSuccess) {
    // fallback: per-step pre-GEMM + step kernel
    for (int t = 0; t < 256; ++t) {
      gemm_pre<<<dim3(1, 40), 256, 0, stream>>>(xb, xdb, Wb, bias5, P, t);
      lstm_step<<<dim3(4, 64), 64, 0, stream>>>(h0, cbuf, Whb, P, hs, t);
    }
  }

  gemm_post<<<dim3(256, 8), 256, 0, stream>>>(xb, hs, Wb + 5 * 524288,
                                              Whb + 3 * 1048576, Wrb, y);
  finish_kernel<<<512, 256, 0, stream>>>(hs, cbuf, y + 33554432);
}